// Round 2
// baseline (17932.166 us; speedup 1.0000x reference)
//
#include <hip/hip_runtime.h>

#define EDGES 400000
#define NN 25000
#define BB 2
#define FCIN 64
#define FCHID 256
#define NCH 288
#define EPB 16
#define NBIN_PAD 25024   // NN rounded up

static_assert(EDGES % EPB == 0, "EPB must divide E");

// ---------------- counting-sort helpers ----------------

__global__ void k_hist(const int* __restrict__ edst, unsigned* __restrict__ cnt) {
    int i = blockIdx.x * 256 + threadIdx.x;
    if (i < EDGES) atomicAdd(&cnt[edst[i]], 1u);
}

// single block, 1024 threads: exclusive scan of cnt[0..NN) -> cur[]
__global__ __launch_bounds__(1024) void k_scan(const unsigned* __restrict__ cnt,
                                               unsigned* __restrict__ cur) {
    __shared__ unsigned s_wt[16];
    __shared__ unsigned s_carry;
    const int t = threadIdx.x, lane = t & 63, wid = t >> 6;
    if (t == 0) s_carry = 0u;
    __syncthreads();
    for (int base = 0; base < NN; base += 1024) {
        int i = base + t;
        unsigned v = (i < NN) ? cnt[i] : 0u;
        unsigned incl = v;
        #pragma unroll
        for (int d = 1; d < 64; d <<= 1) {
            unsigned u = __shfl_up(incl, d);
            if (lane >= d) incl += u;
        }
        if (lane == 63) s_wt[wid] = incl;
        __syncthreads();
        if (wid == 0 && lane < 16) {
            unsigned wv = s_wt[lane];
            unsigned wincl = wv;
            #pragma unroll
            for (int d = 1; d < 16; d <<= 1) {
                unsigned u = __shfl_up(wincl, d);
                if (lane >= d) wincl += u;
            }
            s_wt[lane] = wincl;
        }
        __syncthreads();
        unsigned waveoff = (wid > 0) ? s_wt[wid - 1] : 0u;
        unsigned carry = s_carry;
        if (i < NN) cur[i] = carry + waveoff + incl - v;
        __syncthreads();
        if (t == 1023) s_carry = carry + s_wt[15];
        __syncthreads();
    }
}

__global__ void k_perm(const int* __restrict__ edst, unsigned* __restrict__ cur,
                       unsigned* __restrict__ perm) {
    int i = blockIdx.x * 256 + threadIdx.x;
    if (i < EDGES) {
        unsigned p = atomicAdd(&cur[edst[i]], 1u);
        perm[p] = (unsigned)i;
    }
}

// ---------------- fused conv kernel ----------------
// SORTED=1: edge ids come from perm[] (dst-sorted); same-dst runs are reduced
// in registers and emitted as ONE atomic per run.
template <bool SORTED>
__global__ __launch_bounds__(256, 4) void conv_fused(
    const int* __restrict__ esrc, const int* __restrict__ edst,
    const float* __restrict__ nemb, const float* __restrict__ etype,
    const float* __restrict__ W1, const float* __restrict__ W2,
    const unsigned* __restrict__ perm,
    float* __restrict__ out)
{
    __shared__ __align__(16) float s_h[EPB][FCHID];   // 16 KB
    __shared__ __align__(16) float s_u[EPB][96];      // 6 KB: etype[0..63] then w[0..95]
    __shared__ float s_geom[EPB][BB][9];
    __shared__ int s_dst[EPB];
    __shared__ int s_eidx[EPB];

    const int t = threadIdx.x;
    const size_t slot0 = (size_t)blockIdx.x * EPB;

    if (t < EPB) {
        int e = SORTED ? (int)perm[slot0 + t] : (int)(slot0 + t);
        s_eidx[t] = e;
        s_dst[t] = edst[e];
    }
    __syncthreads();

    // ---- stage edge_type rows into s_u[r][0..63] (rows gathered, 256B each) ----
    {
        int r = t >> 4, q = t & 15;
        const float4* src = (const float4*)(etype + (size_t)s_eidx[r] * FCIN);
        *(float4*)&s_u[r][q * 4] = src[q];
    }
    // ---- geometry for (edge e, batch b): threads 0..31 ----
    if (t < EPB * BB) {
        int e = t >> 1, b = t & 1;
        int s = esrc[s_eidx[e]];
        int d = s_dst[e];
        const float* xp = nemb + ((size_t)b * NN + s) * 3;
        const float* yp = nemb + ((size_t)b * NN + d) * 3;
        float x0 = xp[0], x1 = xp[1], x2 = xp[2];
        float y0 = yp[0], y1 = yp[1], y2 = yp[2];
        const float inv3 = 0.5773502691896258f;
        const float inv2 = 0.7071067811865476f;
        const float inv6 = 0.4082482904638630f;
        s_geom[e][b][0] = (x0*y0 + x1*y1 + x2*y2) * inv3;
        s_geom[e][b][1] = (x1*y2 - x2*y1) * inv2;
        s_geom[e][b][2] = (x2*y0 - x0*y2) * inv2;
        s_geom[e][b][3] = (x0*y1 - x1*y0) * inv2;
        s_geom[e][b][4] = (x0*y1 + x1*y0) * inv2;
        s_geom[e][b][5] = (x1*y2 + x2*y1) * inv2;
        s_geom[e][b][6] = (x0*y2 + x2*y0) * inv2;
        s_geom[e][b][7] = (x0*y0 - x1*y1) * inv2;
        s_geom[e][b][8] = (2.0f*x2*y2 - x0*y0 - x1*y1) * inv6;
    }
    __syncthreads();

    // ---- layer 1: thread t owns hidden unit j=t, K-chunked (regs bounded) ----
    {
        float acc[EPB];
        #pragma unroll
        for (int e = 0; e < EPB; ++e) acc[e] = 0.f;
        #pragma unroll
        for (int kc = 0; kc < 4; ++kc) {
            float w1c[16];
            #pragma unroll
            for (int kk = 0; kk < 16; ++kk) w1c[kk] = W1[(kc * 16 + kk) * FCHID + t];
            #pragma unroll
            for (int e = 0; e < EPB; ++e) {
                #pragma unroll
                for (int q = 0; q < 4; ++q) {
                    float4 ev = *(const float4*)&s_u[e][kc * 16 + q * 4]; // uniform broadcast
                    acc[e] = fmaf(ev.x, w1c[q*4+0], acc[e]);
                    acc[e] = fmaf(ev.y, w1c[q*4+1], acc[e]);
                    acc[e] = fmaf(ev.z, w1c[q*4+2], acc[e]);
                    acc[e] = fmaf(ev.w, w1c[q*4+3], acc[e]);
                }
            }
        }
        #pragma unroll
        for (int e = 0; e < EPB; ++e) {
            float pre = acc[e] * 0.125f;                 // 1/sqrt(64)
            s_h[e][t] = pre / (1.f + __expf(-pre));      // silu
        }
    }
    __syncthreads();   // s_h ready; s_u's etype contents now dead

    // ---- layer 2: threads 0..191: j=t>>1 column, kh=t&1 K-half, K-chunked ----
    if (t < 192) {
        int j = t >> 1, kh = t & 1;
        float acc[EPB];
        #pragma unroll
        for (int e = 0; e < EPB; ++e) acc[e] = 0.f;
        #pragma unroll
        for (int kc = 0; kc < 4; ++kc) {
            float w2c[32];
            #pragma unroll
            for (int kk = 0; kk < 32; ++kk) w2c[kk] = W2[(kh * 128 + kc * 32 + kk) * 96 + j];
            #pragma unroll
            for (int e = 0; e < EPB; ++e) {
                #pragma unroll
                for (int q = 0; q < 8; ++q) {
                    float4 hv = *(const float4*)&s_h[e][kh * 128 + kc * 32 + q * 4];
                    acc[e] = fmaf(hv.x, w2c[q*4+0], acc[e]);
                    acc[e] = fmaf(hv.y, w2c[q*4+1], acc[e]);
                    acc[e] = fmaf(hv.z, w2c[q*4+2], acc[e]);
                    acc[e] = fmaf(hv.w, w2c[q*4+3], acc[e]);
                }
            }
        }
        #pragma unroll
        for (int e = 0; e < EPB; ++e) {
            float v = acc[e] + __shfl_xor(acc[e], 1);    // combine K-halves
            if (kh == 0) s_u[e][j] = v * (0.0625f * 0.25f); // 1/sqrt(256)*1/sqrt(16)
        }
    }
    __syncthreads();

    // ---- tensor product + run-grouped scatter ----
    for (int idx = t; idx < NCH * BB; idx += 256) {
        int b = idx >= NCH;
        int c = b ? idx - NCH : idx;
        unsigned wi, gi;
        if (c < 32)       { wi = c;                          gi = 0; }
        else if (c < 128) { unsigned q = c - 32;  wi = 32 + q / 3u; gi = 1 + q % 3u; }
        else              { unsigned q = c - 128; wi = 64 + q / 5u; gi = 4 + q % 5u; }
        float acc = 0.f;
        int prev = s_dst[0];
        #pragma unroll
        for (int e = 0; e < EPB; ++e) {
            int d = s_dst[e];                            // wave-uniform branch
            if (d != prev) {
                atomicAdd(&out[((size_t)b * NN + prev) * NCH + c], acc);
                acc = 0.f; prev = d;
            }
            acc = fmaf(s_u[e][wi], s_geom[e][b][gi], acc);
        }
        atomicAdd(&out[((size_t)b * NN + prev) * NCH + c], acc);
    }
}

extern "C" void kernel_launch(void* const* d_in, const int* in_sizes, int n_in,
                              void* d_out, int out_size, void* d_ws, size_t ws_size,
                              hipStream_t stream) {
    const int*   esrc  = (const int*)d_in[0];
    const int*   edst  = (const int*)d_in[1];
    const float* nemb  = (const float*)d_in[2];
    const float* etype = (const float*)d_in[3];
    const float* W1    = (const float*)d_in[4];
    const float* W2    = (const float*)d_in[5];
    float* out = (float*)d_out;

    hipMemsetAsync(out, 0, (size_t)out_size * sizeof(float), stream);

    const size_t ws_needed = (size_t)(2 * NBIN_PAD + EDGES) * sizeof(unsigned);
    if (ws_size >= ws_needed) {
        unsigned* cnt  = (unsigned*)d_ws;
        unsigned* cur  = cnt + NBIN_PAD;
        unsigned* perm = cur + NBIN_PAD;
        hipMemsetAsync(cnt, 0, NBIN_PAD * sizeof(unsigned), stream);
        k_hist<<<(EDGES + 255) / 256, 256, 0, stream>>>(edst, cnt);
        k_scan<<<1, 1024, 0, stream>>>(cnt, cur);
        k_perm<<<(EDGES + 255) / 256, 256, 0, stream>>>(edst, cur, perm);
        conv_fused<true><<<EDGES / EPB, 256, 0, stream>>>(
            esrc, edst, nemb, etype, W1, W2, perm, out);
    } else {
        conv_fused<false><<<EDGES / EPB, 256, 0, stream>>>(
            esrc, edst, nemb, etype, W1, W2, nullptr, out);
    }
}

// Round 3
// 334.617 us; speedup vs baseline: 53.5902x; 53.5902x over previous
//
#include <hip/hip_runtime.h>

#define EDGES 400000
#define NN 25000
#define NCH 288
#define EPB 32
#define NBLK (EDGES / EPB)
#define NBIN_PAD 25024

#define W1FRAG 16384   // 2 k2 * 16 nt * 64 lane * 8 el
#define W2FRAG 24576   // 8 k8 * 6 nt * 64 lane * 8 el

typedef float f32x4 __attribute__((ext_vector_type(4)));
typedef short short8 __attribute__((ext_vector_type(8)));

__device__ __forceinline__ unsigned short f2bf(float x) {
    unsigned u = __float_as_uint(x);
    unsigned r = (u + 0x7fffu + ((u >> 16) & 1u)) >> 16;
    return (unsigned short)r;
}
__device__ __forceinline__ float bf2f(unsigned short h) {
    return __uint_as_float(((unsigned)h) << 16);
}

// ---------------- weight -> fragment-order bf16 hi/lo precompute ----------------
__global__ void k_wfrag(const float* __restrict__ W1, const float* __restrict__ W2,
                        unsigned short* __restrict__ w1h, unsigned short* __restrict__ w1l,
                        unsigned short* __restrict__ w2h, unsigned short* __restrict__ w2l) {
    int i = blockIdx.x * 256 + threadIdx.x;
    if (i < W1FRAG) {
        int j = i & 7, l = (i >> 3) & 63, nt = (i >> 9) & 15, k2 = (i >> 13) & 1;
        int n = nt * 16 + (l & 15), k = k2 * 32 + ((l >> 4) * 8) + j;
        float v = W1[k * 256 + n] * 0.125f;              // fold 1/sqrt(64)
        unsigned short hb = f2bf(v);
        w1h[i] = hb; w1l[i] = f2bf(v - bf2f(hb));
    } else if (i < W1FRAG + W2FRAG) {
        int i2 = i - W1FRAG;
        int j = i2 & 7, l = (i2 >> 3) & 63, r = i2 >> 9;  // r in [0,48)
        int nt = r % 6, k8 = r / 6;
        int n = nt * 16 + (l & 15), k = k8 * 32 + ((l >> 4) * 8) + j;
        float v = W2[k * 96 + n] * 0.015625f;            // fold 1/sqrt(256)*1/sqrt(16)
        unsigned short hb = f2bf(v);
        w2h[i2] = hb; w2l[i2] = f2bf(v - bf2f(hb));
    }
}

// ---------------- counting sort (dst-ordered edges) ----------------
__global__ void k_hist(const int* __restrict__ edst, unsigned* __restrict__ cnt) {
    int i = blockIdx.x * 256 + threadIdx.x;
    if (i < EDGES) atomicAdd(&cnt[edst[i]], 1u);
}

__global__ __launch_bounds__(1024) void k_scan(const unsigned* __restrict__ cnt,
                                               unsigned* __restrict__ cur) {
    __shared__ unsigned s_wt[16];
    __shared__ unsigned s_carry;
    const int t = threadIdx.x, lane = t & 63, wid = t >> 6;
    if (t == 0) s_carry = 0u;
    __syncthreads();
    for (int base = 0; base < NN; base += 1024) {
        int i = base + t;
        unsigned v = (i < NN) ? cnt[i] : 0u;
        unsigned incl = v;
        #pragma unroll
        for (int d = 1; d < 64; d <<= 1) {
            unsigned u = __shfl_up(incl, d);
            if (lane >= d) incl += u;
        }
        if (lane == 63) s_wt[wid] = incl;
        __syncthreads();
        if (wid == 0 && lane < 16) {
            unsigned wincl = s_wt[lane];
            #pragma unroll
            for (int d = 1; d < 16; d <<= 1) {
                unsigned u = __shfl_up(wincl, d);
                if (lane >= d) wincl += u;
            }
            s_wt[lane] = wincl;
        }
        __syncthreads();
        unsigned waveoff = (wid > 0) ? s_wt[wid - 1] : 0u;
        unsigned carry = s_carry;
        if (i < NN) cur[i] = carry + waveoff + incl - v;
        __syncthreads();
        if (t == 1023) s_carry = carry + s_wt[15];
        __syncthreads();
    }
}

__global__ void k_perm(const int* __restrict__ edst, unsigned* __restrict__ cur,
                       unsigned* __restrict__ perm) {
    int i = blockIdx.x * 256 + threadIdx.x;
    if (i < EDGES) {
        unsigned p = atomicAdd(&cur[edst[i]], 1u);
        perm[p] = (unsigned)i;
    }
}

// ---------------- fused MFMA conv ----------------
struct SMemU {
    union {
        unsigned short a1[2][EPB * 64];   // etype tile hi/lo (bf16), swizzled  (8 KB)
        float sw[EPB * 100];              // w values after L2 (12.8 KB)
    };
};

template <bool SORTED>
__global__ __launch_bounds__(256) void conv_mfma(
    const int* __restrict__ esrc, const int* __restrict__ edst,
    const float* __restrict__ nemb, const float* __restrict__ etype,
    const unsigned short* __restrict__ w1h, const unsigned short* __restrict__ w1l,
    const unsigned short* __restrict__ w2h, const unsigned short* __restrict__ w2l,
    const unsigned* __restrict__ perm,
    float* __restrict__ out)
{
    __shared__ SMemU U;
    __shared__ unsigned short a2h[EPB * 256];  // h hi (bf16), swizzled (16 KB)
    __shared__ unsigned short a2l[EPB * 256];  // h lo              (16 KB)
    __shared__ float geom[EPB][2][9];
    __shared__ int s_eidx[EPB], s_dst[EPB];

    const int t = threadIdx.x;
    const int lane = t & 63, w = t >> 6;
    const int g = lane >> 4, ln15 = lane & 15;
    const size_t slot0 = (size_t)blockIdx.x * EPB;

    if (t < EPB) {
        int e = SORTED ? (int)perm[slot0 + t] : (int)(slot0 + t);
        s_eidx[t] = e;
        s_dst[t] = edst[e];
    }
    __syncthreads();

    // ---- stage etype tile -> bf16 hi/lo in LDS (XOR-swizzled rows of 128B) ----
    #pragma unroll
    for (int i = 0; i < 2; ++i) {
        int row = i * 16 + (t >> 4);
        int q = t & 15;
        const float4* src = (const float4*)(etype + (size_t)s_eidx[row] * 64);
        float4 v = src[q];
        unsigned short h0 = f2bf(v.x), h1 = f2bf(v.y), h2 = f2bf(v.z), h3 = f2bf(v.w);
        unsigned short l0 = f2bf(v.x - bf2f(h0)), l1 = f2bf(v.y - bf2f(h1));
        unsigned short l2 = f2bf(v.z - bf2f(h2)), l3 = f2bf(v.w - bf2f(h3));
        int boff = row * 128 + ((q * 8) ^ ((row & 7) << 4));
        *(uint2*)((char*)U.a1[0] + boff) = make_uint2((unsigned)h0 | ((unsigned)h1 << 16),
                                                      (unsigned)h2 | ((unsigned)h3 << 16));
        *(uint2*)((char*)U.a1[1] + boff) = make_uint2((unsigned)l0 | ((unsigned)l1 << 16),
                                                      (unsigned)l2 | ((unsigned)l3 << 16));
    }
    // ---- geometry (threads 0..63) ----
    if (t < EPB * 2) {
        int e = t >> 1, b = t & 1;
        int sn = esrc[s_eidx[e]], dn = s_dst[e];
        const float* xp = nemb + ((size_t)b * NN + sn) * 3;
        const float* yp = nemb + ((size_t)b * NN + dn) * 3;
        float x0 = xp[0], x1 = xp[1], x2 = xp[2];
        float y0 = yp[0], y1 = yp[1], y2 = yp[2];
        const float inv3 = 0.5773502691896258f;
        const float inv2 = 0.7071067811865476f;
        const float inv6 = 0.4082482904638630f;
        geom[e][b][0] = (x0*y0 + x1*y1 + x2*y2) * inv3;
        geom[e][b][1] = (x1*y2 - x2*y1) * inv2;
        geom[e][b][2] = (x2*y0 - x0*y2) * inv2;
        geom[e][b][3] = (x0*y1 - x1*y0) * inv2;
        geom[e][b][4] = (x0*y1 + x1*y0) * inv2;
        geom[e][b][5] = (x1*y2 + x2*y1) * inv2;
        geom[e][b][6] = (x0*y2 + x2*y0) * inv2;
        geom[e][b][7] = (x0*y0 - x1*y1) * inv2;
        geom[e][b][8] = (2.0f*x2*y2 - x0*y0 - x1*y1) * inv6;
    }
    __syncthreads();

    // ---- layer 1 MFMA: [32e x 64k] @ [64k x 256n], wave w owns n-tiles 4w..4w+3 ----
    f32x4 acc1[2][4];
    #pragma unroll
    for (int m = 0; m < 2; ++m)
        #pragma unroll
        for (int n = 0; n < 4; ++n)
            #pragma unroll
            for (int r = 0; r < 4; ++r) acc1[m][n][r] = 0.f;

    #pragma unroll
    for (int k2 = 0; k2 < 2; ++k2) {
        short8 bh[4], bl[4];
        #pragma unroll
        for (int n = 0; n < 4; ++n) {
            int idx = ((k2 * 16 + (4 * w + n)) * 64 + lane) * 8;
            bh[n] = *(const short8*)(w1h + idx);
            bl[n] = *(const short8*)(w1l + idx);
        }
        #pragma unroll
        for (int m = 0; m < 2; ++m) {
            int row = m * 16 + ln15;
            int boff = row * 128 + (((k2 * 64) + g * 16) ^ ((row & 7) << 4));
            short8 ah = *(const short8*)((const char*)U.a1[0] + boff);
            short8 al = *(const short8*)((const char*)U.a1[1] + boff);
            #pragma unroll
            for (int n = 0; n < 4; ++n)
                acc1[m][n] = __builtin_amdgcn_mfma_f32_16x16x32_bf16(ah, bh[n], acc1[m][n], 0, 0, 0);
            #pragma unroll
            for (int n = 0; n < 4; ++n)
                acc1[m][n] = __builtin_amdgcn_mfma_f32_16x16x32_bf16(ah, bl[n], acc1[m][n], 0, 0, 0);
            #pragma unroll
            for (int n = 0; n < 4; ++n)
                acc1[m][n] = __builtin_amdgcn_mfma_f32_16x16x32_bf16(al, bh[n], acc1[m][n], 0, 0, 0);
        }
    }

    // ---- silu + split -> A2 (h) in LDS ----
    #pragma unroll
    for (int m = 0; m < 2; ++m) {
        #pragma unroll
        for (int n = 0; n < 4; ++n) {
            int nt = 4 * w + n;
            #pragma unroll
            for (int r = 0; r < 4; ++r) {
                float pre = acc1[m][n][r];
                float hv = pre / (1.f + __expf(-pre));
                int e = m * 16 + g * 4 + r;
                int col = nt * 16 + ln15;
                unsigned short hh = f2bf(hv);
                unsigned short hl = f2bf(hv - bf2f(hh));
                int boff = e * 512 + ((col * 2) ^ ((e & 7) << 4));
                *(unsigned short*)((char*)a2h + boff) = hh;
                *(unsigned short*)((char*)a2l + boff) = hl;
            }
        }
    }
    __syncthreads();

    // ---- layer 2 MFMA: [32e x 256k] @ [256k x 96n]; wave: m2=w>>1, n-tiles nb..nb+2 ----
    const int m2 = w >> 1, nb = 3 * (w & 1);
    f32x4 acc2[3];
    #pragma unroll
    for (int n = 0; n < 3; ++n)
        #pragma unroll
        for (int r = 0; r < 4; ++r) acc2[n][r] = 0.f;

    #pragma unroll
    for (int k8 = 0; k8 < 8; ++k8) {
        int row = m2 * 16 + ln15;
        int boff = row * 512 + ((k8 * 64 + g * 16) ^ ((row & 7) << 4));
        short8 ah = *(const short8*)((const char*)a2h + boff);
        short8 al = *(const short8*)((const char*)a2l + boff);
        short8 bh[3], bl[3];
        #pragma unroll
        for (int n = 0; n < 3; ++n) {
            int idx = ((k8 * 6 + nb + n) * 64 + lane) * 8;
            bh[n] = *(const short8*)(w2h + idx);
            bl[n] = *(const short8*)(w2l + idx);
        }
        #pragma unroll
        for (int n = 0; n < 3; ++n)
            acc2[n] = __builtin_amdgcn_mfma_f32_16x16x32_bf16(ah, bh[n], acc2[n], 0, 0, 0);
        #pragma unroll
        for (int n = 0; n < 3; ++n)
            acc2[n] = __builtin_amdgcn_mfma_f32_16x16x32_bf16(ah, bl[n], acc2[n], 0, 0, 0);
        #pragma unroll
        for (int n = 0; n < 3; ++n)
            acc2[n] = __builtin_amdgcn_mfma_f32_16x16x32_bf16(al, bh[n], acc2[n], 0, 0, 0);
    }
    __syncthreads();   // a1 region dead for everyone; safe to overwrite as sw

    // ---- write w to LDS (padded stride 100) ----
    #pragma unroll
    for (int n = 0; n < 3; ++n) {
        int c = (nb + n) * 16 + ln15;
        #pragma unroll
        for (int r = 0; r < 4; ++r) {
            int e = m2 * 16 + g * 4 + r;
            U.sw[e * 100 + c] = acc2[n][r];
        }
    }
    __syncthreads();

    // ---- tensor product + run-grouped scatter ----
    for (int idx = t; idx < NCH * 2; idx += 256) {
        int b = idx >= NCH;
        int c = idx - b * NCH;
        unsigned wi, gi;
        if (c < 32)       { wi = c;                          gi = 0; }
        else if (c < 128) { unsigned q = c - 32;  wi = 32 + q / 3u; gi = 1 + q % 3u; }
        else              { unsigned q = c - 128; wi = 64 + q / 5u; gi = 4 + q % 5u; }
        float acc = 0.f;
        int prev = s_dst[0];
        #pragma unroll 4
        for (int e = 0; e < EPB; ++e) {
            int d = s_dst[e];                      // wave-uniform
            if (d != prev) {
                atomicAdd(&out[((size_t)b * NN + prev) * NCH + c], acc);
                acc = 0.f; prev = d;
            }
            acc = fmaf(U.sw[e * 100 + wi], geom[e][b][gi], acc);
        }
        atomicAdd(&out[((size_t)b * NN + prev) * NCH + c], acc);
    }
}

extern "C" void kernel_launch(void* const* d_in, const int* in_sizes, int n_in,
                              void* d_out, int out_size, void* d_ws, size_t ws_size,
                              hipStream_t stream) {
    const int*   esrc  = (const int*)d_in[0];
    const int*   edst  = (const int*)d_in[1];
    const float* nemb  = (const float*)d_in[2];
    const float* etype = (const float*)d_in[3];
    const float* W1    = (const float*)d_in[4];
    const float* W2    = (const float*)d_in[5];
    float* out = (float*)d_out;

    hipMemsetAsync(out, 0, (size_t)out_size * sizeof(float), stream);

    unsigned short* w1h = (unsigned short*)d_ws;
    unsigned short* w1l = w1h + W1FRAG;
    unsigned short* w2h = w1l + W1FRAG;
    unsigned short* w2l = w2h + W2FRAG;
    const size_t frag_bytes = (size_t)(2 * W1FRAG + 2 * W2FRAG) * sizeof(unsigned short);

    k_wfrag<<<(W1FRAG + W2FRAG + 255) / 256, 256, 0, stream>>>(W1, W2, w1h, w1l, w2h, w2l);

    const size_t sort_bytes = (size_t)(2 * NBIN_PAD + EDGES) * sizeof(unsigned);
    if (ws_size >= frag_bytes + sort_bytes) {
        unsigned* cnt  = (unsigned*)((char*)d_ws + frag_bytes);
        unsigned* cur  = cnt + NBIN_PAD;
        unsigned* perm = cur + NBIN_PAD;
        hipMemsetAsync(cnt, 0, NBIN_PAD * sizeof(unsigned), stream);
        k_hist<<<(EDGES + 255) / 256, 256, 0, stream>>>(edst, cnt);
        k_scan<<<1, 1024, 0, stream>>>(cnt, cur);
        k_perm<<<(EDGES + 255) / 256, 256, 0, stream>>>(edst, cur, perm);
        conv_mfma<true><<<NBLK, 256, 0, stream>>>(
            esrc, edst, nemb, etype, w1h, w1l, w2h, w2l, perm, out);
    } else {
        conv_mfma<false><<<NBLK, 256, 0, stream>>>(
            esrc, edst, nemb, etype, w1h, w1l, w2h, w2l, nullptr, out);
    }
}

// Round 4
// 306.233 us; speedup vs baseline: 58.5572x; 1.0927x over previous
//
#include <hip/hip_runtime.h>

#define EDGES 400000
#define NN 25000
#define NCH 288
#define EPB 32
#define NBLK (EDGES / EPB)
#define NBIN_PAD 25024

#define W1FRAG 16384   // 2 k2 * 16 nt * 64 lane * 8 el
#define W2FRAG 24576   // 8 k8 * 6 nt * 64 lane * 8 el

typedef float f32x4 __attribute__((ext_vector_type(4)));
typedef short short8 __attribute__((ext_vector_type(8)));

__device__ __forceinline__ unsigned short f2bf(float x) {          // RNE
    unsigned u = __float_as_uint(x);
    unsigned r = (u + 0x7fffu + ((u >> 16) & 1u)) >> 16;
    return (unsigned short)r;
}
__device__ __forceinline__ unsigned short f2bf_t(float x) {        // truncate (lo planes)
    return (unsigned short)(__float_as_uint(x) >> 16);
}
__device__ __forceinline__ float bf2f(unsigned short h) {
    return __uint_as_float(((unsigned)h) << 16);
}

// ---------------- weight -> fragment-order bf16 hi/lo precompute ----------------
__global__ void k_wfrag(const float* __restrict__ W1, const float* __restrict__ W2,
                        unsigned short* __restrict__ w1h, unsigned short* __restrict__ w1l,
                        unsigned short* __restrict__ w2h, unsigned short* __restrict__ w2l) {
    int i = blockIdx.x * 256 + threadIdx.x;
    if (i < W1FRAG) {
        int j = i & 7, l = (i >> 3) & 63, nt = (i >> 9) & 15, k2 = (i >> 13) & 1;
        int n = nt * 16 + (l & 15), k = k2 * 32 + ((l >> 4) * 8) + j;
        float v = W1[k * 256 + n] * 0.125f;              // fold 1/sqrt(64)
        unsigned short hb = f2bf(v);
        w1h[i] = hb; w1l[i] = f2bf_t(v - bf2f(hb));
    } else if (i < W1FRAG + W2FRAG) {
        int i2 = i - W1FRAG;
        int j = i2 & 7, l = (i2 >> 3) & 63, r = i2 >> 9;  // r in [0,48)
        int nt = r % 6, k8 = r / 6;
        int n = nt * 16 + (l & 15), k = k8 * 32 + ((l >> 4) * 8) + j;
        float v = W2[k * 96 + n] * 0.015625f;            // fold 1/sqrt(256)*1/sqrt(16)
        unsigned short hb = f2bf(v);
        w2h[i2] = hb; w2l[i2] = f2bf_t(v - bf2f(hb));
    }
}

// ---------------- counting sort (dst-ordered edges) ----------------
__global__ void k_hist(const int* __restrict__ edst, unsigned* __restrict__ cnt) {
    int i = blockIdx.x * 256 + threadIdx.x;
    if (i < EDGES) atomicAdd(&cnt[edst[i]], 1u);
}

__global__ __launch_bounds__(1024) void k_scan(const unsigned* __restrict__ cnt,
                                               unsigned* __restrict__ cur) {
    __shared__ unsigned s_wt[16];
    __shared__ unsigned s_carry;
    const int t = threadIdx.x, lane = t & 63, wid = t >> 6;
    if (t == 0) s_carry = 0u;
    __syncthreads();
    for (int base = 0; base < NN; base += 1024) {
        int i = base + t;
        unsigned v = (i < NN) ? cnt[i] : 0u;
        unsigned incl = v;
        #pragma unroll
        for (int d = 1; d < 64; d <<= 1) {
            unsigned u = __shfl_up(incl, d);
            if (lane >= d) incl += u;
        }
        if (lane == 63) s_wt[wid] = incl;
        __syncthreads();
        if (wid == 0 && lane < 16) {
            unsigned wincl = s_wt[lane];
            #pragma unroll
            for (int d = 1; d < 16; d <<= 1) {
                unsigned u = __shfl_up(wincl, d);
                if (lane >= d) wincl += u;
            }
            s_wt[lane] = wincl;
        }
        __syncthreads();
        unsigned waveoff = (wid > 0) ? s_wt[wid - 1] : 0u;
        unsigned carry = s_carry;
        if (i < NN) cur[i] = carry + waveoff + incl - v;
        __syncthreads();
        if (t == 1023) s_carry = carry + s_wt[15];
        __syncthreads();
    }
}

__global__ void k_perm(const int* __restrict__ edst, unsigned* __restrict__ cur,
                       unsigned* __restrict__ perm) {
    int i = blockIdx.x * 256 + threadIdx.x;
    if (i < EDGES) {
        unsigned p = atomicAdd(&cur[edst[i]], 1u);
        perm[p] = (unsigned)i;
    }
}

// ---------------- fused MFMA conv (half-split h pipeline) ----------------
struct S2 {
    union {
        struct { unsigned short a2h[EPB * 128]; unsigned short a2l[EPB * 128]; }; // 16 KB
        float sw[EPB * 100];                                                      // 12.8 KB
    };
};

template <bool SORTED>
__global__ __launch_bounds__(256) void conv_mfma(
    const int* __restrict__ esrc, const int* __restrict__ edst,
    const float* __restrict__ nemb, const float* __restrict__ etype,
    const unsigned short* __restrict__ w1h, const unsigned short* __restrict__ w1l,
    const unsigned short* __restrict__ w2h, const unsigned short* __restrict__ w2l,
    const unsigned* __restrict__ perm,
    float* __restrict__ out)
{
    __shared__ unsigned short a1h[EPB * 64];   // 4 KB
    __shared__ unsigned short a1l[EPB * 64];   // 4 KB
    __shared__ S2 U2;                          // 16 KB
    __shared__ float geom[EPB][2][9];          // 2.25 KB
    __shared__ int s_eidx[EPB], s_dst[EPB];

    const int t = threadIdx.x;
    const int lane = t & 63, w = t >> 6;
    const int g = lane >> 4, ln15 = lane & 15;
    const size_t slot0 = (size_t)blockIdx.x * EPB;

    if (t < EPB) {
        int e = SORTED ? (int)perm[slot0 + t] : (int)(slot0 + t);
        s_eidx[t] = e;
        s_dst[t] = edst[e];
    }
    __syncthreads();

    // ---- stage etype tile -> bf16 hi/lo in LDS (XOR-swizzled) ----
    #pragma unroll
    for (int i = 0; i < 2; ++i) {
        int f4 = t + 256 * i;                  // 0..511
        int row = f4 >> 4, q = f4 & 15;
        const float4* src = (const float4*)(etype + (size_t)s_eidx[row] * 64);
        float4 v = src[q];
        unsigned short h0 = f2bf(v.x), h1 = f2bf(v.y), h2 = f2bf(v.z), h3 = f2bf(v.w);
        unsigned short l0 = f2bf_t(v.x - bf2f(h0)), l1 = f2bf_t(v.y - bf2f(h1));
        unsigned short l2 = f2bf_t(v.z - bf2f(h2)), l3 = f2bf_t(v.w - bf2f(h3));
        int boff = row * 128 + ((q * 8) ^ ((row & 7) << 4));
        *(uint2*)((char*)a1h + boff) = make_uint2((unsigned)h0 | ((unsigned)h1 << 16),
                                                  (unsigned)h2 | ((unsigned)h3 << 16));
        *(uint2*)((char*)a1l + boff) = make_uint2((unsigned)l0 | ((unsigned)l1 << 16),
                                                  (unsigned)l2 | ((unsigned)l3 << 16));
    }
    // ---- geometry (threads 0..63) ----
    if (t < EPB * 2) {
        int e = t >> 1, b = t & 1;
        int sn = esrc[s_eidx[e]], dn = s_dst[e];
        const float* xp = nemb + ((size_t)b * NN + sn) * 3;
        const float* yp = nemb + ((size_t)b * NN + dn) * 3;
        float x0 = xp[0], x1 = xp[1], x2 = xp[2];
        float y0 = yp[0], y1 = yp[1], y2 = yp[2];
        const float inv3 = 0.5773502691896258f;
        const float inv2 = 0.7071067811865476f;
        const float inv6 = 0.4082482904638630f;
        geom[e][b][0] = (x0*y0 + x1*y1 + x2*y2) * inv3;
        geom[e][b][1] = (x1*y2 - x2*y1) * inv2;
        geom[e][b][2] = (x2*y0 - x0*y2) * inv2;
        geom[e][b][3] = (x0*y1 - x1*y0) * inv2;
        geom[e][b][4] = (x0*y1 + x1*y0) * inv2;
        geom[e][b][5] = (x1*y2 + x2*y1) * inv2;
        geom[e][b][6] = (x0*y2 + x2*y0) * inv2;
        geom[e][b][7] = (x0*y0 - x1*y1) * inv2;
        geom[e][b][8] = (2.0f*x2*y2 - x0*y0 - x1*y1) * inv6;
    }
    __syncthreads();

    // layer-2 accumulators persist across both halves
    const int m2 = w >> 1, nb = 3 * (w & 1);
    f32x4 acc2[3];
    #pragma unroll
    for (int n = 0; n < 3; ++n)
        #pragma unroll
        for (int r = 0; r < 4; ++r) acc2[n][r] = 0.f;

    for (int hf = 0; hf < 2; ++hf) {
        // ---- layer 1 (half): wave w owns n-tiles {hf*8+2w, hf*8+2w+1} ----
        f32x4 acc1[2][2];
        #pragma unroll
        for (int m = 0; m < 2; ++m)
            #pragma unroll
            for (int n = 0; n < 2; ++n)
                #pragma unroll
                for (int r = 0; r < 4; ++r) acc1[m][n][r] = 0.f;

        #pragma unroll
        for (int k2 = 0; k2 < 2; ++k2) {
            short8 bh[2], bl[2];
            #pragma unroll
            for (int n = 0; n < 2; ++n) {
                int idx = ((k2 * 16 + hf * 8 + 2 * w + n) * 64 + lane) * 8;
                bh[n] = *(const short8*)(w1h + idx);
                bl[n] = *(const short8*)(w1l + idx);
            }
            #pragma unroll
            for (int m = 0; m < 2; ++m) {
                int row = m * 16 + ln15;
                int boff = row * 128 + (((k2 * 64) + g * 16) ^ ((row & 7) << 4));
                short8 ah = *(const short8*)((const char*)a1h + boff);
                short8 al = *(const short8*)((const char*)a1l + boff);
                #pragma unroll
                for (int n = 0; n < 2; ++n) {
                    acc1[m][n] = __builtin_amdgcn_mfma_f32_16x16x32_bf16(ah, bh[n], acc1[m][n], 0, 0, 0);
                    acc1[m][n] = __builtin_amdgcn_mfma_f32_16x16x32_bf16(ah, bl[n], acc1[m][n], 0, 0, 0);
                    acc1[m][n] = __builtin_amdgcn_mfma_f32_16x16x32_bf16(al, bh[n], acc1[m][n], 0, 0, 0);
                }
            }
        }

        // ---- silu + split -> half h buffer (cols 0..127 local) ----
        #pragma unroll
        for (int m = 0; m < 2; ++m) {
            #pragma unroll
            for (int n = 0; n < 2; ++n) {
                int col2 = (2 * w + n) * 16 + ln15;      // 0..127
                #pragma unroll
                for (int r = 0; r < 4; ++r) {
                    float pre = acc1[m][n][r];
                    float hv = pre * __builtin_amdgcn_rcpf(1.f + __expf(-pre));
                    int e = m * 16 + g * 4 + r;
                    unsigned short hh = f2bf(hv);
                    unsigned short hl = f2bf_t(hv - bf2f(hh));
                    int boff = e * 256 + ((col2 * 2) ^ ((e & 7) << 4));
                    *(unsigned short*)((char*)U2.a2h + boff) = hh;
                    *(unsigned short*)((char*)U2.a2l + boff) = hl;
                }
            }
        }
        __syncthreads();

        // ---- layer 2 (half): k8 = hf*4 .. hf*4+3 ----
        #pragma unroll
        for (int k4 = 0; k4 < 4; ++k4) {
            int row = m2 * 16 + ln15;
            int boff = row * 256 + ((k4 * 64 + g * 16) ^ ((row & 7) << 4));
            short8 ah = *(const short8*)((const char*)U2.a2h + boff);
            short8 al = *(const short8*)((const char*)U2.a2l + boff);
            int kg = hf * 4 + k4;
            short8 bh[3], bl[3];
            #pragma unroll
            for (int n = 0; n < 3; ++n) {
                int idx = ((kg * 6 + nb + n) * 64 + lane) * 8;
                bh[n] = *(const short8*)(w2h + idx);
                bl[n] = *(const short8*)(w2l + idx);
            }
            #pragma unroll
            for (int n = 0; n < 3; ++n) {
                acc2[n] = __builtin_amdgcn_mfma_f32_16x16x32_bf16(ah, bh[n], acc2[n], 0, 0, 0);
                acc2[n] = __builtin_amdgcn_mfma_f32_16x16x32_bf16(ah, bl[n], acc2[n], 0, 0, 0);
                acc2[n] = __builtin_amdgcn_mfma_f32_16x16x32_bf16(al, bh[n], acc2[n], 0, 0, 0);
            }
        }
        __syncthreads();   // h half consumed; safe to overwrite next iter (or as sw)
    }

    // ---- write w to LDS (overlays dead a2 region; padded stride 100) ----
    #pragma unroll
    for (int n = 0; n < 3; ++n) {
        int c = (nb + n) * 16 + ln15;
        #pragma unroll
        for (int r = 0; r < 4; ++r) {
            int e = m2 * 16 + g * 4 + r;
            U2.sw[e * 100 + c] = acc2[n][r];
        }
    }
    __syncthreads();

    // ---- tensor product + run-grouped scatter (interior runs: plain store) ----
    for (int idx = t; idx < NCH * 2; idx += 256) {
        int b = idx >= NCH;
        int c = idx - b * NCH;
        unsigned wi, gi;
        if (c < 32)       { wi = c;                          gi = 0; }
        else if (c < 128) { unsigned q = c - 32;  wi = 32 + q / 3u; gi = 1 + q % 3u; }
        else              { unsigned q = c - 128; wi = 64 + q / 5u; gi = 4 + q % 5u; }
        float acc = 0.f;
        int prev = s_dst[0];
        int rs = 0;
        #pragma unroll 4
        for (int e = 0; e < EPB; ++e) {
            int d = s_dst[e];                      // wave-uniform
            if (d != prev) {
                float* addr = &out[((size_t)b * NN + prev) * NCH + c];
                if (SORTED && rs > 0) *addr = acc;     // interior run: exclusive owner
                else atomicAdd(addr, acc);             // boundary run
                acc = 0.f; prev = d; rs = e;
            }
            acc = fmaf(U2.sw[e * 100 + wi], geom[e][b][gi], acc);
        }
        atomicAdd(&out[((size_t)b * NN + prev) * NCH + c], acc);  // last run: boundary
    }
}

extern "C" void kernel_launch(void* const* d_in, const int* in_sizes, int n_in,
                              void* d_out, int out_size, void* d_ws, size_t ws_size,
                              hipStream_t stream) {
    const int*   esrc  = (const int*)d_in[0];
    const int*   edst  = (const int*)d_in[1];
    const float* nemb  = (const float*)d_in[2];
    const float* etype = (const float*)d_in[3];
    const float* W1    = (const float*)d_in[4];
    const float* W2    = (const float*)d_in[5];
    float* out = (float*)d_out;

    hipMemsetAsync(out, 0, (size_t)out_size * sizeof(float), stream);

    unsigned short* w1h = (unsigned short*)d_ws;
    unsigned short* w1l = w1h + W1FRAG;
    unsigned short* w2h = w1l + W1FRAG;
    unsigned short* w2l = w2h + W2FRAG;
    const size_t frag_bytes = (size_t)(2 * W1FRAG + 2 * W2FRAG) * sizeof(unsigned short);

    k_wfrag<<<(W1FRAG + W2FRAG + 255) / 256, 256, 0, stream>>>(W1, W2, w1h, w1l, w2h, w2l);

    const size_t sort_bytes = (size_t)(2 * NBIN_PAD + EDGES) * sizeof(unsigned);
    if (ws_size >= frag_bytes + sort_bytes) {
        unsigned* cnt  = (unsigned*)((char*)d_ws + frag_bytes);
        unsigned* cur  = cnt + NBIN_PAD;
        unsigned* perm = cur + NBIN_PAD;
        hipMemsetAsync(cnt, 0, NBIN_PAD * sizeof(unsigned), stream);
        k_hist<<<(EDGES + 255) / 256, 256, 0, stream>>>(edst, cnt);
        k_scan<<<1, 1024, 0, stream>>>(cnt, cur);
        k_perm<<<(EDGES + 255) / 256, 256, 0, stream>>>(edst, cur, perm);
        conv_mfma<true><<<NBLK, 256, 0, stream>>>(
            esrc, edst, nemb, etype, w1h, w1l, w2h, w2l, perm, out);
    } else {
        conv_mfma<false><<<NBLK, 256, 0, stream>>>(
            esrc, edst, nemb, etype, w1h, w1l, w2h, w2l, nullptr, out);
    }
}